// Round 1
// baseline (26299.249 us; speedup 1.0000x reference)
//
#include <hip/hip_runtime.h>
#include <math.h>

#define TSTEPS 16384
#define NTAGS  1024
#define NWG    32
#define RPW    32      // rows per workgroup
#define TPB    1024
#define START_I 1022
#define STOP_I  1023

// Persistent-kernel CRF forward in the linear (exp) domain.
//  p_{t+1} = e_t ⊙ (M · (p_t / max(p_t))),  S += log(max(p_t))
//  answer  = S + log( Σ_i p_T[i] · exp(trans[STOP,i]) )
// Cross-workgroup dependency carried by a depth-2 ring of self-validating
// values: stored v = sign(t) * (p + 1), sign flips every ring wrap, so
// poison (0xAA -> -3e-13) and stale (opposite-sign) entries never validate.
// All ring traffic uses agent-scope atomics (coherent at LLC across XCDs).

__global__ __launch_bounds__(TPB, 4)
void crf_forward_kernel(const float* __restrict__ decoded,
                        const float* __restrict__ trans,
                        float* __restrict__ out,
                        float* __restrict__ ring)
{
    __shared__ float lds_p[NTAGS];
    __shared__ float lds_red[2][16 * 32];
    __shared__ float lds_max[2][16];

    const int tid  = threadIdx.x;
    const int wg   = blockIdx.x;
    const int lane = tid & 63;
    const int wid  = tid >> 6;
    const int row  = tid & 31;   // local row index (0..31)
    const int sub  = tid >> 5;   // 32-wide column chunk (0..31)

    // Preload this thread's M fragment: M[wg*32+row][sub*32+k], k=0..31 (32 VGPRs)
    float M[32];
    {
        const float* tr = trans + (size_t)(wg * RPW + row) * NTAGS + sub * 32;
        #pragma unroll
        for (int k = 0; k < 32; ++k) M[k] = __expf(tr[k]);
    }

    const bool isw0 = (wid == 0);
    double s2 = 0.0;   // sum of log2(m_t); maintained uniformly by wave 0
    float dcur = 0.0f; // decoded[t][wg*32 + (lane&31)], wave-0 prefetch pipeline
    if (isw0) dcur = decoded[(size_t)wg * RPW + (lane & 31)];

    for (int t = 0; t < TSTEPS; ++t) {
        // ---- obtain p_t[tid] ----
        float pv;
        if (t == 0) {
            pv = (tid == START_I) ? 1.0f : 0.0f;   // exp(init): one-hot at START
        } else {
            const float sgn = ((t >> 1) & 1) ? -1.0f : 1.0f;
            const float* src = ring + (size_t)(t & 1) * NTAGS + tid;
            float v;
            do {
                v = __hip_atomic_load(src, __ATOMIC_RELAXED, __HIP_MEMORY_SCOPE_AGENT);
                v *= sgn;
            } while (!(v >= 1.0f));   // NaN/poison/stale all keep polling
            pv = v - 1.0f;
        }
        const int par = t & 1;

        // stage p_t into LDS; per-wave max for the global rescale
        lds_p[tid] = pv;
        float wm = pv;
        #pragma unroll
        for (int m = 32; m >= 1; m >>= 1) wm = fmaxf(wm, __shfl_xor(wm, m, 64));
        if (lane == 0) lds_max[par][wid] = wm;
        __syncthreads();

        // ---- partial dot product over this thread's 32-column chunk ----
        float acc = 0.0f;
        {
            const float4* pp = (const float4*)(lds_p + sub * 32);
            #pragma unroll
            for (int q = 0; q < 8; ++q) {
                float4 v4 = pp[q];
                acc = fmaf(M[4*q+0], v4.x, acc);
                acc = fmaf(M[4*q+1], v4.y, acc);
                acc = fmaf(M[4*q+2], v4.z, acc);
                acc = fmaf(M[4*q+3], v4.w, acc);
            }
        }
        acc += __shfl_xor(acc, 32, 64);                  // fold the wave's two chunks
        if (lane < 32) lds_red[par][wid * 32 + lane] = acc;

        // prefetch next step's emissions (pure input -> normal cached load)
        float dnext = 0.0f;
        if (isw0 && (t + 1) < TSTEPS)
            dnext = decoded[(size_t)(t + 1) * NTAGS + wg * RPW + (lane & 31)];
        __syncthreads();

        // ---- wave 0: finish row sums, rescale, publish ----
        if (isw0) {
            const int h = lane >> 5, r = lane & 31;
            float s = 0.0f;
            #pragma unroll
            for (int k = 0; k < 8; ++k) s += lds_red[par][(h * 8 + k) * 32 + r];
            s += __shfl_xor(s, 32, 64);                  // full 1024-wide row sum
            float m = lds_max[par][0];
            #pragma unroll
            for (int k = 1; k < 16; ++k) m = fmaxf(m, lds_max[par][k]);
            const float inv_m = 1.0f / m;                // identical in every wg (same data, same code)
            s2 += (double)__log2f(m);
            const float e = __expf(dcur);
            const float outv = e * s * inv_m;            // p_{t+1}[wg*32 + r]
            const int tn = t + 1;
            const float sg = ((tn >> 1) & 1) ? -1.0f : 1.0f;
            if (lane < 32) {
                __hip_atomic_store(ring + (size_t)(tn & 1) * NTAGS + wg * RPW + r,
                                   sg * (outv + 1.0f),
                                   __ATOMIC_RELAXED, __HIP_MEMORY_SCOPE_AGENT);
            }
            dcur = dnext;
        }
    }

    // ---- epilogue: workgroup 0 folds in trans[STOP,:] and writes alpha ----
    if (wg == 0) {
        const int t = TSTEPS;                            // read p_T
        const float sgn = ((t >> 1) & 1) ? -1.0f : 1.0f;
        const float* src = ring + (size_t)(t & 1) * NTAGS + tid;
        float v;
        do {
            v = __hip_atomic_load(src, __ATOMIC_RELAXED, __HIP_MEMORY_SCOPE_AGENT);
            v *= sgn;
        } while (!(v >= 1.0f));
        float term = (v - 1.0f) * __expf(trans[(size_t)STOP_I * NTAGS + tid]);
        #pragma unroll
        for (int m = 32; m >= 1; m >>= 1) term += __shfl_xor(term, m, 64);
        __syncthreads();
        if (lane == 0) lds_red[0][wid] = term;
        __syncthreads();
        if (tid == 0) {
            double tot = 0.0;
            for (int k = 0; k < 16; ++k) tot += (double)lds_red[0][k];
            out[0] = (float)(0.6931471805599453 * (s2 + log2(tot)));
        }
    }
}

extern "C" void kernel_launch(void* const* d_in, const int* in_sizes, int n_in,
                              void* d_out, int out_size, void* d_ws, size_t ws_size,
                              hipStream_t stream) {
    const float* decoded = (const float*)d_in[0];   // [16384, 1024] f32
    const float* trans   = (const float*)d_in[1];   // [1024, 1024]  f32
    // d_in[2] (raw_outputs) and d_in[3] (outputs) are unused by the reference.
    float* out  = (float*)d_out;
    float* ring = (float*)d_ws;                     // 2 * 1024 floats = 8 KB

    // Make the ring's "invalid" state independent of harness poisoning.
    hipMemsetAsync(ring, 0xAA, 2 * NTAGS * sizeof(float), stream);

    hipLaunchKernelGGL(crf_forward_kernel, dim3(NWG), dim3(TPB), 0, stream,
                       decoded, trans, out, ring);
}

// Round 2
// 21674.188 us; speedup vs baseline: 1.2134x; 1.2134x over previous
//
#include <hip/hip_runtime.h>
#include <math.h>

#define TSTEPS 16384
#define NTAGS  1024
#define NWG    256      // one workgroup per CU
#define TPB    128      // 2 waves; 1 wave per SIMD -> no issue contention
#define START_I 1022
#define STOP_I  1023

// CRF forward in the linear (exp) domain, latency-optimized.
//   p_{t+1} = e_t . (M p_t) / max(p_t),  S += log(max(p_t))
//   alpha   = S + log( sum_i p_T[i] * exp(trans[STOP,i]) )
// No LDS, no barriers: each WAVE polls the full 1024-float vector itself
// (16 values/lane, 8x u64 agent-scope loads, each instruction 512B
// contiguous across lanes). Validation is embedded in the data: stored
// value = sign(t) * (p + 1), sign flips every ring wrap (depth-2 ring),
// so 0xAA poison (-3e-13) and stale opposite-sign values never validate.
// Sign/offset are folded out of the hot path algebraically:
//   sum_c M[r][c]*(sg*v[c]-1) = sg * (sum M v) - (sum M)   (msum precomp)

__global__ __launch_bounds__(TPB)
void crf_forward_kernel(const float* __restrict__ decoded,
                        const float* __restrict__ trans,
                        float* __restrict__ out,
                        float* __restrict__ ring)
{
    const int tid  = threadIdx.x;
    const int wg   = blockIdx.x;
    const int lane = tid & 63;
    const int wid  = tid >> 6;            // 0..1
    const int r0   = wg * 4 + wid * 2;    // this wave's two output tags
    const int r1   = r0 + 1;

    // ---- init: M fragments (cols 128k + 2*lane + h), row sums of M ----
    float Ma[16], Mb[16];
    float sma = 0.0f, smb = 0.0f;
    #pragma unroll
    for (int k = 0; k < 8; ++k) {
        const int c = 128 * k + 2 * lane;
        Ma[2*k]   = __expf(trans[(size_t)r0 * NTAGS + c]);
        Ma[2*k+1] = __expf(trans[(size_t)r0 * NTAGS + c + 1]);
        Mb[2*k]   = __expf(trans[(size_t)r1 * NTAGS + c]);
        Mb[2*k+1] = __expf(trans[(size_t)r1 * NTAGS + c + 1]);
        sma += Ma[2*k] + Ma[2*k+1];
        smb += Mb[2*k] + Mb[2*k+1];
    }
    // reduce M row sums with the SAME lane->row mapping as the step reduce
    sma += __shfl_xor(sma, 32, 64);
    smb += __shfl_xor(smb, 32, 64);
    float msum = (lane & 32) ? smb : sma;
    msum += __shfl_xor(msum, 16, 64);
    msum += __shfl_xor(msum,  8, 64);
    msum += __shfl_xor(msum,  4, 64);
    msum += __shfl_xor(msum,  2, 64);
    msum += __shfl_xor(msum,  1, 64);
    // lanes 0..31 now hold sum(M[r0,:]); lanes 32..63 hold sum(M[r1,:])

    const bool storer = ((lane & 31) == 0);     // lane 0 -> r0, lane 32 -> r1
    const int  myrow  = (lane >> 5) ? r1 : r0;

    double s2   = 0.0;    // sum of log2(max) — maintained uniformly per wave
    float dcur  = 0.0f, dnext = 0.0f;
    if (storer) dcur = decoded[myrow];          // emission for t = 0

    for (int t = 0; t < TSTEPS; ++t) {
        const float e = __expf(dcur);           // off critical path
        if (storer && (t + 1) < TSTEPS)
            dnext = decoded[(size_t)(t + 1) * NTAGS + myrow];

        const float sg = ((t >> 1) & 1) ? -1.0f : 1.0f;

        // ---- obtain raw v (stored-form) for this lane's 16 columns ----
        float v[16];
        if (t == 0) {
            #pragma unroll
            for (int k = 0; k < 8; ++k) {
                const int c = 128 * k + 2 * lane;
                v[2*k]   = (c     == START_I) ? 2.0f : 1.0f;  // pv+1, sg=+1
                v[2*k+1] = (c + 1 == START_I) ? 2.0f : 1.0f;
            }
        } else {
            const unsigned long long* src =
                (const unsigned long long*)(ring + (size_t)(t & 1) * NTAGS) + lane;
            if (sg > 0.0f) {
                for (;;) {
                    unsigned long long q[8];
                    #pragma unroll
                    for (int k = 0; k < 8; ++k)
                        q[k] = __hip_atomic_load(src + 64 * k, __ATOMIC_RELAXED,
                                                 __HIP_MEMORY_SCOPE_AGENT);
                    #pragma unroll
                    for (int k = 0; k < 8; ++k) {
                        v[2*k]   = __uint_as_float((unsigned)q[k]);
                        v[2*k+1] = __uint_as_float((unsigned)(q[k] >> 32));
                    }
                    float mn = v[0];
                    #pragma unroll
                    for (int j = 1; j < 16; ++j) mn = fminf(mn, v[j]);
                    if (mn >= 1.0f) break;      // all 16 valid
                }
            } else {
                for (;;) {
                    unsigned long long q[8];
                    #pragma unroll
                    for (int k = 0; k < 8; ++k)
                        q[k] = __hip_atomic_load(src + 64 * k, __ATOMIC_RELAXED,
                                                 __HIP_MEMORY_SCOPE_AGENT);
                    #pragma unroll
                    for (int k = 0; k < 8; ++k) {
                        v[2*k]   = __uint_as_float((unsigned)q[k]);
                        v[2*k+1] = __uint_as_float((unsigned)(q[k] >> 32));
                    }
                    float mx = v[0];
                    #pragma unroll
                    for (int j = 1; j < 16; ++j) mx = fmaxf(mx, v[j]);
                    if (mx <= -1.0f) break;
                }
            }
        }

        // ---- per-lane raw extreme (for the global max of pv) ----
        float Eraw = v[0];
        if (sg > 0.0f) {
            #pragma unroll
            for (int j = 1; j < 16; ++j) Eraw = fmaxf(Eraw, v[j]);
        } else {
            #pragma unroll
            for (int j = 1; j < 16; ++j) Eraw = fminf(Eraw, v[j]);
        }

        // ---- dot products on raw v (sign/offset folded into msum) ----
        float a0 = 0.0f, a1 = 0.0f;
        #pragma unroll
        for (int j = 0; j < 16; ++j) {
            a0 = fmaf(Ma[j], v[j], a0);
            a1 = fmaf(Mb[j], v[j], a1);
        }

        // global max of pv across the wave (exact, associative)
        float ml = fmaf(sg, Eraw, -1.0f);
        ml = fmaxf(ml, __shfl_xor(ml, 32, 64));
        ml = fmaxf(ml, __shfl_xor(ml, 16, 64));
        ml = fmaxf(ml, __shfl_xor(ml,  8, 64));
        ml = fmaxf(ml, __shfl_xor(ml,  4, 64));
        ml = fmaxf(ml, __shfl_xor(ml,  2, 64));
        ml = fmaxf(ml, __shfl_xor(ml,  1, 64));

        // row-sum butterfly: pack two rows into the two half-waves
        a0 += __shfl_xor(a0, 32, 64);
        a1 += __shfl_xor(a1, 32, 64);
        float b = (lane & 32) ? a1 : a0;
        b += __shfl_xor(b, 16, 64);
        b += __shfl_xor(b,  8, 64);
        b += __shfl_xor(b,  4, 64);
        b += __shfl_xor(b,  2, 64);
        b += __shfl_xor(b,  1, 64);

        s2 += (double)__log2f(ml);              // off critical path

        if (storer) {
            const float s    = fmaf(sg, b, -msum);            // sum M . pv
            const float outv = e * s * __builtin_amdgcn_rcpf(ml);
            const int   tn   = t + 1;
            const float sgn  = ((tn >> 1) & 1) ? -1.0f : 1.0f;
            __hip_atomic_store(ring + (size_t)(tn & 1) * NTAGS + myrow,
                               fmaf(sgn, outv, sgn),          // sgn*(outv+1)
                               __ATOMIC_RELAXED, __HIP_MEMORY_SCOPE_AGENT);
        }
        dcur = dnext;
    }

    // ---- epilogue: wg0/wave0 folds in trans[STOP,:] ----
    if (wg == 0 && wid == 0) {
        // p_T lives in slot (TSTEPS&1)=0 with sign +1 ((TSTEPS>>1)&1 = 0)
        const unsigned long long* src = (const unsigned long long*)ring + lane;
        float v[16];
        for (;;) {
            unsigned long long q[8];
            #pragma unroll
            for (int k = 0; k < 8; ++k)
                q[k] = __hip_atomic_load(src + 64 * k, __ATOMIC_RELAXED,
                                         __HIP_MEMORY_SCOPE_AGENT);
            #pragma unroll
            for (int k = 0; k < 8; ++k) {
                v[2*k]   = __uint_as_float((unsigned)q[k]);
                v[2*k+1] = __uint_as_float((unsigned)(q[k] >> 32));
            }
            float mn = v[0];
            #pragma unroll
            for (int j = 1; j < 16; ++j) mn = fminf(mn, v[j]);
            if (mn >= 1.0f) break;
        }
        float term = 0.0f;
        #pragma unroll
        for (int k = 0; k < 8; ++k) {
            const int c = 128 * k + 2 * lane;
            term = fmaf(__expf(trans[(size_t)STOP_I * NTAGS + c]),
                        v[2*k] - 1.0f, term);
            term = fmaf(__expf(trans[(size_t)STOP_I * NTAGS + c + 1]),
                        v[2*k+1] - 1.0f, term);
        }
        term += __shfl_xor(term, 32, 64);
        term += __shfl_xor(term, 16, 64);
        term += __shfl_xor(term,  8, 64);
        term += __shfl_xor(term,  4, 64);
        term += __shfl_xor(term,  2, 64);
        term += __shfl_xor(term,  1, 64);
        if (lane == 0)
            out[0] = (float)(0.6931471805599453 * (s2 + log2((double)term)));
    }
}

extern "C" void kernel_launch(void* const* d_in, const int* in_sizes, int n_in,
                              void* d_out, int out_size, void* d_ws, size_t ws_size,
                              hipStream_t stream) {
    const float* decoded = (const float*)d_in[0];   // [16384, 1024] f32
    const float* trans   = (const float*)d_in[1];   // [1024, 1024]  f32
    float* out  = (float*)d_out;
    float* ring = (float*)d_ws;                     // 2 * 1024 floats = 8 KB

    // Ring "invalid" state independent of harness poisoning (0xAA already
    // invalid, but enforce it ourselves for replay safety).
    hipMemsetAsync(ring, 0xAA, 2 * NTAGS * sizeof(float), stream);

    hipLaunchKernelGGL(crf_forward_kernel, dim3(NWG), dim3(TPB), 0, stream,
                       decoded, trans, out, ring);
}